// Round 1
// baseline (1015.634 us; speedup 1.0000x reference)
//
#include <hip/hip_runtime.h>

#define TPB 256

static inline int cdiv(int a, int b) { return (a + b - 1) / b; }

// ---------------------------------------------------------------------------
// Scale-0 cost volume: cost[b,h,w,d] = sum_c |fl[b,h,w,c] - fr[b,h,w-d,c]|,
// fr treated as 0 where w < d. Output layout (B,H,W,D), d fastest.
// ---------------------------------------------------------------------------
template <int C>
__global__ void cost0_kernel(const float* __restrict__ fl, const float* __restrict__ fr,
                             float* __restrict__ out, int B, int H, int W, int D) {
    int idx = blockIdx.x * blockDim.x + threadIdx.x;
    int total = B * H * W * D;
    if (idx >= total) return;
    int d = idx % D; int t = idx / D;
    int w = t % W;   t /= W;
    int h = t % H;   int b = t / H;
    const float* pl = fl + (size_t)((b * H + h) * W + w) * C;
    float s = 0.f;
    if (w >= d) {
        const float* pr = fr + (size_t)((b * H + h) * W + (w - d)) * C;
#pragma unroll
        for (int c = 0; c < C; ++c) s += fabsf(pl[c] - pr[c]);
    } else {
#pragma unroll
        for (int c = 0; c < C; ++c) s += fabsf(pl[c]);
    }
    out[idx] = s;
}

// ---------------------------------------------------------------------------
// _build_volume_2d3 with faithful TF tile+reshape scrambling.
// For reshaped row n = a*K + t, element (n,y,x,c) of bfl/bfr maps to source
// flat rem = t*H*W*C + y*W*C + x*C + c decomposed in (H,W,C,K) strides.
// Flow bd(n,y,x) maps via rem2 = t*H*W + y*W + x in (H,W,1,K) strides.
// Output written at flat (n*H + y)*W + x  ==  (B,H,W,K) view for the conv.
// ---------------------------------------------------------------------------
template <int C, int K, int W>
__global__ void cost2d3_kernel(const float* __restrict__ fl, const float* __restrict__ fr,
                               const float* __restrict__ wflow, float* __restrict__ out,
                               int B, int H, int md) {
    int idx = blockIdx.x * blockDim.x + threadIdx.x;
    int total = B * K * H * W;
    if (idx >= total) return;
    int x = idx % W; int t0 = idx / W;
    int y = t0 % H;  int n = t0 / H;
    int a = n / K, t = n % K;

    // flow value (scrambled indexing into wflow)
    int rem2 = (t * H + y) * W + x;
    int hd = rem2 / (W * K);
    int wd = (rem2 / K) % W;
    float bd = wflow[(a * H + hd) * W + wd] - (float)(t - md + 1);

    float xq = (float)x - bd;
    xq = fminf(fmaxf(xq, 0.f), (float)(W - 1));
    int x0 = (int)floorf(xq);
    if (x0 > W - 2) x0 = W - 2;
    float al = xq - (float)x0;

    int base  = ((t * H + y) * W + x)  * C;
    int base0 = ((t * H + y) * W + x0) * C;
    int base1 = base0 + C;

    float s = 0.f;
#pragma unroll
    for (int c = 0; c < C; ++c) {
        int r = base + c;
        int h1 = r / (W * C * K); int w1 = (r / (C * K)) % W; int c1 = (r / K) % C;
        float av = fl[((a * H + h1) * W + w1) * C + c1];

        int r0 = base0 + c;
        int h0 = r0 / (W * C * K); int w0 = (r0 / (C * K)) % W; int c0 = (r0 / K) % C;
        float f0 = fr[((a * H + h0) * W + w0) * C + c0];

        int r1 = base1 + c;
        int h1b = r1 / (W * C * K); int w1b = (r1 / (C * K)) % W; int c1b = (r1 / K) % C;
        float f1 = fr[((a * H + h1b) * W + w1b) * C + c1b];

        float wv = f0 * (1.f - al) + f1 * al;
        s += fabsf(av - wv);
    }
    out[idx] = s;
}

// ---------------------------------------------------------------------------
// Generic 3x3x3 SAME conv over dims (D1,D2,D3), channels-last.
// Weights (3,3,3,CIN,COUT) staged in LDS; one thread per voxel, all COUT.
// ---------------------------------------------------------------------------
template <int CIN, int COUT, bool RELU>
__global__ void conv3d_kernel(const float* __restrict__ in, const float* __restrict__ wsrc,
                              float* __restrict__ out, int B, int D1, int D2, int D3) {
    constexpr int WSZ = 27 * CIN * COUT;
    __shared__ float ws[WSZ];
    for (int i = threadIdx.x; i < WSZ; i += blockDim.x) ws[i] = wsrc[i];
    __syncthreads();

    int idx = blockIdx.x * blockDim.x + threadIdx.x;
    int total = B * D1 * D2 * D3;
    if (idx >= total) return;
    int d3 = idx % D3; int t = idx / D3;
    int d2 = t % D2;   t /= D2;
    int d1 = t % D1;   int b = t / D1;

    float acc[COUT];
#pragma unroll
    for (int co = 0; co < COUT; ++co) acc[co] = 0.f;

    for (int kd = 0; kd < 3; ++kd) {
        int z = d1 + kd - 1; if (z < 0 || z >= D1) continue;
        for (int kh = 0; kh < 3; ++kh) {
            int y = d2 + kh - 1; if (y < 0 || y >= D2) continue;
            int rowbase = ((b * D1 + z) * D2 + y) * D3;
            for (int kw = 0; kw < 3; ++kw) {
                int x = d3 + kw - 1; if (x < 0 || x >= D3) continue;
                const float* ip = in + (size_t)(rowbase + x) * CIN;
                const float* wp = ws + ((kd * 3 + kh) * 3 + kw) * CIN * COUT;
#pragma unroll
                for (int ci = 0; ci < CIN; ++ci) {
                    float v = ip[ci];
                    if constexpr (COUT % 4 == 0) {
                        const float4* w4 = (const float4*)(wp + ci * COUT);
#pragma unroll
                        for (int q = 0; q < COUT / 4; ++q) {
                            float4 wv = w4[q];
                            acc[q * 4 + 0] += v * wv.x;
                            acc[q * 4 + 1] += v * wv.y;
                            acc[q * 4 + 2] += v * wv.z;
                            acc[q * 4 + 3] += v * wv.w;
                        }
                    } else {
#pragma unroll
                        for (int co = 0; co < COUT; ++co) acc[co] += v * wp[ci * COUT + co];
                    }
                }
            }
        }
    }

    float* op = out + (size_t)idx * COUT;
#pragma unroll
    for (int co = 0; co < COUT; ++co) op[co] = RELU ? fmaxf(acc[co], 0.f) : acc[co];
}

// ---------------------------------------------------------------------------
// softmax(-cost) over last dim D, weighted by dvals = dstart + d
// ---------------------------------------------------------------------------
__global__ void softargmax_kernel(const float* __restrict__ in, float* __restrict__ out,
                                  int npix, int D, float dstart) {
    int idx = blockIdx.x * blockDim.x + threadIdx.x;
    if (idx >= npix) return;
    const float* p = in + (size_t)idx * D;
    float m = -1e30f;
    for (int d = 0; d < D; ++d) m = fmaxf(m, -p[d]);
    float s = 0.f, wsum = 0.f;
    for (int d = 0; d < D; ++d) {
        float e = expf(-p[d] - m);
        s += e;
        wsum += e * (dstart + (float)d);
    }
    out[idx] = wsum / s;
}

// ---------------------------------------------------------------------------
// Bilinear upsample (jax.image.resize 'bilinear', upscale => half-pixel +
// edge renormalization == clamp). Optional add of prev prediction.
// ---------------------------------------------------------------------------
__global__ void upsample_kernel(const float* __restrict__ disp, int inH, int inW,
                                const float* __restrict__ prev, float* __restrict__ out,
                                int B, int OH, int OW) {
    int idx = blockIdx.x * blockDim.x + threadIdx.x;
    int total = B * OH * OW;
    if (idx >= total) return;
    int x = idx % OW; int t = idx / OW;
    int y = t % OH;   int b = t / OH;
    float sy = (y + 0.5f) * ((float)inH / (float)OH) - 0.5f;
    float sx = (x + 0.5f) * ((float)inW / (float)OW) - 0.5f;
    sy = fminf(fmaxf(sy, 0.f), (float)(inH - 1));
    sx = fminf(fmaxf(sx, 0.f), (float)(inW - 1));
    int y0 = (int)sy; if (y0 > inH - 2) y0 = inH - 2;
    int x0 = (int)sx; if (x0 > inW - 2) x0 = inW - 2;
    float ay = sy - (float)y0, ax = sx - (float)x0;
    const float* p = disp + (size_t)(b * inH + y0) * inW + x0;
    float v00 = p[0], v01 = p[1], v10 = p[inW], v11 = p[inW + 1];
    float v0 = v00 * (1.f - ax) + v01 * ax;
    float v1 = v10 * (1.f - ax) + v11 * ax;
    float v  = v0 * (1.f - ay) + v1 * ay;
    if (prev) v += prev[idx];
    out[idx] = v;
}

// ---------------------------------------------------------------------------
// Antialiased bilinear downsample by integer factor F (jax resize default
// antialias=True): triangle kernel of radius F, weights renormalized over
// valid taps. Result multiplied by `mult`.
// ---------------------------------------------------------------------------
__global__ void downsample_kernel(const float* __restrict__ in, int inH, int inW,
                                  float* __restrict__ out, int B, int OH, int OW,
                                  int F, float mult) {
    int idx = blockIdx.x * blockDim.x + threadIdx.x;
    int total = B * OH * OW;
    if (idx >= total) return;
    int x = idx % OW; int t = idx / OW;
    int y = t % OH;   int b = t / OH;
    float sy = (y + 0.5f) * (float)F - 0.5f;
    float sx = (x + 0.5f) * (float)F - 0.5f;
    float invF = 1.f / (float)F;
    int jlo = (int)floorf(sy) - F + 1, jhi = (int)floorf(sy) + F;
    int ilo = (int)floorf(sx) - F + 1, ihi = (int)floorf(sx) + F;

    float wxsum = 0.f;
    for (int i = ilo; i <= ihi; ++i) {
        if (i < 0 || i >= inW) continue;
        float wx = 1.f - fabsf(sx - (float)i) * invF;
        if (wx > 0.f) wxsum += wx;
    }
    float wysum = 0.f, acc = 0.f;
    for (int j = jlo; j <= jhi; ++j) {
        if (j < 0 || j >= inH) continue;
        float wy = 1.f - fabsf(sy - (float)j) * invF;
        if (wy <= 0.f) continue;
        wysum += wy;
        const float* row = in + (size_t)(b * inH + j) * inW;
        float r = 0.f;
        for (int i = ilo; i <= ihi; ++i) {
            if (i < 0 || i >= inW) continue;
            float wx = 1.f - fabsf(sx - (float)i) * invF;
            if (wx > 0.f) r += wx * row[i];
        }
        acc += wy * r;
    }
    out[idx] = mult * acc / (wysum * wxsum);
}

// ---------------------------------------------------------------------------

extern "C" void kernel_launch(void* const* d_in, const int* in_sizes, int n_in,
                              void* d_out, int out_size, void* d_ws, size_t ws_size,
                              hipStream_t stream) {
    const float* fl0 = (const float*)d_in[0];
    const float* fr0 = (const float*)d_in[1];
    const float* fl1 = (const float*)d_in[2];
    const float* fr1 = (const float*)d_in[3];
    const float* fl2 = (const float*)d_in[4];
    const float* fr2 = (const float*)d_in[5];
    const float* w0_in  = (const float*)d_in[6];
    const float* w0_mid = (const float*)d_in[7];
    const float* w0_out = (const float*)d_in[8];
    const float* w1_in  = (const float*)d_in[9];
    const float* w1_mid = (const float*)d_in[10];
    const float* w1_out = (const float*)d_in[11];
    const float* w2_in  = (const float*)d_in[12];
    const float* w2_mid = (const float*)d_in[13];
    const float* w2_out = (const float*)d_in[14];
    float* out = (float*)d_out;

    const int B = 16;
    const int OH = 512, OW = 1024;
    const int P = B * OH * OW;            // one prediction block (fp32 elements)

    const size_t BUF = 10485760;          // max conv volume: 16*128*256*5*4
    float* bufA  = (float*)d_ws;
    float* bufB  = bufA + BUF;
    float* disp  = bufB + BUF;
    float* wflow = disp + 524288;

    // ======================= scale 0 =======================
    {
        const int H = 32, W = 64, D = 12;
        int vox = B * H * W * D;
        cost0_kernel<16><<<cdiv(vox, TPB), TPB, 0, stream>>>(fl0, fr0, bufA, B, H, W, D);
        conv3d_kernel<1, 16, true ><<<cdiv(vox, TPB), TPB, 0, stream>>>(bufA, w0_in,           bufB, B, H, W, D);
        conv3d_kernel<16, 16, true><<<cdiv(vox, TPB), TPB, 0, stream>>>(bufB, w0_mid,          bufA, B, H, W, D);
        conv3d_kernel<16, 16, true><<<cdiv(vox, TPB), TPB, 0, stream>>>(bufA, w0_mid + 6912,   bufB, B, H, W, D);
        conv3d_kernel<16, 16, true><<<cdiv(vox, TPB), TPB, 0, stream>>>(bufB, w0_mid + 13824,  bufA, B, H, W, D);
        conv3d_kernel<16, 1, false><<<cdiv(vox, TPB), TPB, 0, stream>>>(bufA, w0_out,          bufB, B, H, W, D);
        softargmax_kernel<<<cdiv(B * H * W, TPB), TPB, 0, stream>>>(bufB, disp, B * H * W, D, 0.f);
        upsample_kernel<<<cdiv(P, TPB), TPB, 0, stream>>>(disp, H, W, nullptr, out, B, OH, OW);
    }

    // ======================= scale 1 =======================
    {
        const int H = 64, W = 128, K = 5, md = 3;
        downsample_kernel<<<cdiv(B * H * W, TPB), TPB, 0, stream>>>(out, OH, OW, wflow, B, H, W, 8, 64.f / 512.f);
        int vox = B * K * H * W;
        cost2d3_kernel<16, 5, 128><<<cdiv(vox, TPB), TPB, 0, stream>>>(fl1, fr1, wflow, bufA, B, H, md);
        conv3d_kernel<1, 4, true ><<<cdiv(vox, TPB), TPB, 0, stream>>>(bufA, w1_in,        bufB, B, H, W, K);
        conv3d_kernel<4, 4, true ><<<cdiv(vox, TPB), TPB, 0, stream>>>(bufB, w1_mid,       bufA, B, H, W, K);
        conv3d_kernel<4, 4, true ><<<cdiv(vox, TPB), TPB, 0, stream>>>(bufA, w1_mid + 432, bufB, B, H, W, K);
        conv3d_kernel<4, 4, true ><<<cdiv(vox, TPB), TPB, 0, stream>>>(bufB, w1_mid + 864, bufA, B, H, W, K);
        conv3d_kernel<4, 1, false><<<cdiv(vox, TPB), TPB, 0, stream>>>(bufA, w1_out,       bufB, B, H, W, K);
        softargmax_kernel<<<cdiv(B * H * W, TPB), TPB, 0, stream>>>(bufB, disp, B * H * W, K, -2.f);
        upsample_kernel<<<cdiv(P, TPB), TPB, 0, stream>>>(disp, H, W, out, out + P, B, OH, OW);
    }

    // ======================= scale 2 =======================
    {
        const int H = 128, W = 256, K = 5, md = 3;
        downsample_kernel<<<cdiv(B * H * W, TPB), TPB, 0, stream>>>(out + P, OH, OW, wflow, B, H, W, 4, 128.f / 512.f);
        int vox = B * K * H * W;
        cost2d3_kernel<16, 5, 256><<<cdiv(vox, TPB), TPB, 0, stream>>>(fl2, fr2, wflow, bufA, B, H, md);
        conv3d_kernel<1, 4, true ><<<cdiv(vox, TPB), TPB, 0, stream>>>(bufA, w2_in,        bufB, B, H, W, K);
        conv3d_kernel<4, 4, true ><<<cdiv(vox, TPB), TPB, 0, stream>>>(bufB, w2_mid,       bufA, B, H, W, K);
        conv3d_kernel<4, 4, true ><<<cdiv(vox, TPB), TPB, 0, stream>>>(bufA, w2_mid + 432, bufB, B, H, W, K);
        conv3d_kernel<4, 4, true ><<<cdiv(vox, TPB), TPB, 0, stream>>>(bufB, w2_mid + 864, bufA, B, H, W, K);
        conv3d_kernel<4, 1, false><<<cdiv(vox, TPB), TPB, 0, stream>>>(bufA, w2_out,       bufB, B, H, W, K);
        softargmax_kernel<<<cdiv(B * H * W, TPB), TPB, 0, stream>>>(bufB, disp, B * H * W, K, -2.f);
        upsample_kernel<<<cdiv(P, TPB), TPB, 0, stream>>>(disp, H, W, out + P, out + 2 * P, B, OH, OW);
    }
}